// Round 9
// baseline (738.145 us; speedup 1.0000x reference)
//
#include <hip/hip_runtime.h>
#include <cstdint>

typedef unsigned short u16;
typedef __bf16 bf16x8 __attribute__((ext_vector_type(8)));
typedef float f32x4 __attribute__((ext_vector_type(4)));

#define L_ 2048
#define S_ 2048
#define B_ 4
#define E_ 1024
#define H_ 16
#define FF_ 4096
#define M_ (L_*B_)

#define QK_SCALE 0.18033688f   /* 1/sqrt(64) * log2(e) */

__device__ __forceinline__ unsigned f2bf(float f) {
  unsigned u = __float_as_uint(f);
  return (u + 0x7fffu + ((u >> 16) & 1u)) >> 16;
}
__device__ __forceinline__ float bflo(unsigned u){ return __uint_as_float(u << 16); }
__device__ __forceinline__ float bfhi(unsigned u){ return __uint_as_float(u & 0xffff0000u); }

// ---------------- batched f32 -> bf16 conversion ----------------
struct CvtSeg { const float* src; u16* dst; int blk_end; };
struct CvtTab { CvtSeg s[6]; };

__global__ __launch_bounds__(256) void cvt_all(CvtTab t, int nseg) {
  const int blk = blockIdx.x;
  int k = 0;
  while (k < nseg - 1 && blk >= t.s[k].blk_end) k++;
  const int b0 = (k == 0) ? 0 : t.s[k-1].blk_end;
  const int off = (blk - b0) * 1024 + threadIdx.x * 4;
  float4 f = *(const float4*)(t.s[k].src + off);
  uint2 u;
  u.x = f2bf(f.x) | (f2bf(f.y) << 16);
  u.y = f2bf(f.z) | (f2bf(f.w) << 16);
  *(uint2*)(t.s[k].dst + off) = u;
}

// ---------------- shared helpers ----------------
struct GTab { u16* o[3]; const float* b[3]; float sc[3]; };

__device__ __forceinline__ void gl_lds16(const u16* g, u16* l) {
  __builtin_amdgcn_global_load_lds(
      (const __attribute__((address_space(1))) unsigned int*)g,
      (__attribute__((address_space(3))) unsigned int*)l, 16, 0, 0);
}

// Compiler-fenced raw barrier: no vmcnt(0) drain (unlike __syncthreads()).
#define RAW_BARRIER() do { \
  asm volatile("" ::: "memory"); \
  __builtin_amdgcn_s_barrier(); \
  asm volatile("" ::: "memory"); \
} while (0)

// ---------------- 256x256-tile counted-vmcnt GEMM ----------------
// R8: same XCD pathology as gemm256n had (R7): XCD = linear_id%8, so blocks
// sharing an A-panel sat on 8 different XCDs -> per-XCD L2 refetch (FFN1:
// FETCH 73.8 MB vs 24 ideal, MfmaUtil 32%). Bijective remap: XCD owns a
// contiguous 4-panel bm-stripe (2 MB A, L2-resident); the 4 blocks of each
// bn-group dispatch together -> B-panel read ~once per XCD per bn.
template<int RELU, int NG>
__global__ __launch_bounds__(512, 2) void gemm256(
    const u16* __restrict__ A,
    const u16* __restrict__ Bw,
    GTab t, int K, int N)
{
  extern __shared__ __align__(16) u16 LDs[];   // 65536 u16 = 128 KB
  const int tid  = threadIdx.x;
  const int lane = tid & 63;
  const int quad = lane >> 4;
  const int l16  = lane & 15;
  const int w    = tid >> 6;
  const int wm   = w >> 2;            // 0..1  (row half)
  const int wn   = w & 3;             // 0..3  (col quarter)

  // XCD-locality remap: lid%8 = XCD; XCD x owns bm-stripe [4x, 4x+4).
  const int lid = (int)(blockIdx.y * gridDim.x + blockIdx.x);
  const int loc = lid >> 3;
  const int bmq = ((lid & 7) << 2) + (loc & 3);   // 0..31
  const int bnq = loc >> 2;                        // 0..gridDim.x-1
  const int bm = bmq << 8;
  const int bn = bnq << 8;

  const int grp = (NG > 1) ? (bnq >> 2) : 0;
  u16* Cb = t.o[grp];
  const float* bias = t.b[grp];
  const float scale = t.sc[grp];
  const int ld = (NG > 1) ? 1024 : N;

  const int srow = (w << 4) + (lane >> 2);
  const int cg8  = ((lane & 3) ^ ((lane >> 3) & 3)) << 3;
  const u16* pa0 = A  + (size_t)(bm + srow) * K + cg8;          // A rows [0,128)
  const u16* pa1 = pa0 + (size_t)128 * K;                        // A rows [128,256)
  const u16* pb0 = Bw + (size_t)(bn + srow) * K + cg8;          // B rows [0,128)
  const u16* pb1 = pb0 + (size_t)128 * K;                        // B rows [128,256)
  const int wds = w << 9;  // wave's 1KB slice (elements) within an 8KB half

  const int swz  = (quad ^ ((l16 >> 1) & 3)) << 3;
  const int aoff = ((wm << 7) + l16) * 32 + swz;            // + mt*512
  const int boff = 8192 + ((wn << 6) + l16) * 32 + swz;     // + nt*512

  f32x4 acc[8][4];
  #pragma unroll
  for (int i = 0; i < 8; i++)
    #pragma unroll
    for (int j = 0; j < 4; j++)
      acc[i][j] = (f32x4){0.f, 0.f, 0.f, 0.f};

  const int nk = K >> 5;

  #pragma unroll
  for (int kt = 0; kt < 3; kt++) {
    const int sb = kt << 14;
    gl_lds16(pa0 + kt*32, LDs + sb + wds);
    gl_lds16(pa1 + kt*32, LDs + sb + 4096  + wds);
    gl_lds16(pb0 + kt*32, LDs + sb + 8192  + wds);
    gl_lds16(pb1 + kt*32, LDs + sb + 12288 + wds);
  }
  pa0 += 96; pa1 += 96; pb0 += 96; pb1 += 96;   // -> tile 3
  asm volatile("s_waitcnt vmcnt(8)" ::: "memory");
  RAW_BARRIER();

  for (int it = 0; it < nk; ++it) {
    const int rb = (it & 3) << 14;          // read buffer (tile it)
    const int sb = ((it + 3) & 3) << 14;    // stage buffer (tile it+3 / dummy)

    bf16x8 bfr[4], afr[4];
    #pragma unroll
    for (int nt = 0; nt < 4; nt++)
      bfr[nt] = *(const bf16x8*)(LDs + rb + boff + nt*512);
    #pragma unroll
    for (int mt = 0; mt < 4; mt++)
      afr[mt] = *(const bf16x8*)(LDs + rb + aoff + mt*512);
    gl_lds16(pa0, LDs + sb + wds);
    gl_lds16(pa1, LDs + sb + 4096 + wds);
    RAW_BARRIER();
    __builtin_amdgcn_s_setprio(1);
    #pragma unroll
    for (int mt = 0; mt < 4; mt++)
      #pragma unroll
      for (int nt = 0; nt < 4; nt++)
        acc[mt][nt] = __builtin_amdgcn_mfma_f32_16x16x32_bf16(afr[mt], bfr[nt], acc[mt][nt], 0, 0, 0);
    __builtin_amdgcn_s_setprio(0);
    RAW_BARRIER();

    #pragma unroll
    for (int mt = 0; mt < 4; mt++)
      afr[mt] = *(const bf16x8*)(LDs + rb + aoff + (4 + mt)*512);
    gl_lds16(pb0, LDs + sb + 8192  + wds);
    gl_lds16(pb1, LDs + sb + 12288 + wds);
    asm volatile("s_waitcnt vmcnt(8)" ::: "memory");   // forces ALL of tile it+1
    RAW_BARRIER();
    __builtin_amdgcn_s_setprio(1);
    #pragma unroll
    for (int mt = 0; mt < 4; mt++)
      #pragma unroll
      for (int nt = 0; nt < 4; nt++)
        acc[4 + mt][nt] = __builtin_amdgcn_mfma_f32_16x16x32_bf16(afr[mt], bfr[nt], acc[4 + mt][nt], 0, 0, 0);
    __builtin_amdgcn_s_setprio(0);
    RAW_BARRIER();

    if (it + 4 < nk) { pa0 += 32; pa1 += 32; pb0 += 32; pb1 += 32; }
  }

  #pragma unroll
  for (int nt = 0; nt < 4; nt++) {
    const int col = bn + (wn << 6) + nt*16 + l16;
    const int ocol = (NG > 1) ? (col & 1023) : col;
    const float bv = bias[ocol];
    #pragma unroll
    for (int mt = 0; mt < 8; mt++) {
      #pragma unroll
      for (int i = 0; i < 4; i++) {
        const int row = bm + (wm << 7) + mt*16 + quad*4 + i;
        float v = (acc[mt][nt][i] + bv) * scale;
        if (RELU) v = fmaxf(v, 0.0f);
        Cb[(size_t)row * ld + ocol] = (u16)f2bf(v);
      }
    }
  }
}

// ---------------- 256x128-tile counted-vmcnt GEMM (N=1024 outputs) ----------
// R7 remap: XCD bx owns bm-stripe [4bx,4bx+4); ring-5 + vmcnt(9) from R6.
template<int RELU>
__global__ __launch_bounds__(512, 2) void gemm256n(
    const u16* __restrict__ A,
    const u16* __restrict__ Bw,
    const float* __restrict__ bias,
    u16* __restrict__ C,
    float scale, int K, int N)
{
  extern __shared__ __align__(16) u16 LDs[];   // 61440 u16 = 120 KB (5 x 24KB)
  const int tid  = threadIdx.x;
  const int lane = tid & 63;
  const int quad = lane >> 4;
  const int l16  = lane & 15;
  const int w    = tid >> 6;
  const int wm   = w >> 1;            // 0..3  (row quarter, 64 rows)
  const int wn   = w & 1;             // 0..1  (col half, 64 cols)

  // XCD-locality remap (grid is (8,32); XCD = (by*8+bx)%8 = bx)
  const int bx = blockIdx.x, by = blockIdx.y;
  const int bmq = (bx << 2) + (by & 3);   // 0..31, XCD bx -> bm-stripe [4bx,4bx+4)
  const int bnq = by >> 2;                // 0..7
  const int bm = bmq << 8;     // 256 rows
  const int bn = bnq << 7;     // 128 cols

  const int srow = (w << 4) + (lane >> 2);                    // 0..127
  const int cg8  = ((lane & 3) ^ ((lane >> 3) & 3)) << 3;
  const u16* pa0 = A  + (size_t)(bm + srow) * K + cg8;        // A rows [0,128)
  const u16* pa1 = pa0 + (size_t)128 * K;                      // A rows [128,256)
  const u16* pb0 = Bw + (size_t)(bn + srow) * K + cg8;        // B rows [0,128)
  const int wds = w << 9;

  const int swz  = (quad ^ ((l16 >> 1) & 3)) << 3;
  const int aoff = ((wm << 6) + l16) * 32 + swz;            // + mt*512
  const int boff = 8192 + ((wn << 6) + l16) * 32 + swz;     // + nt*512

  f32x4 acc[4][4];
  #pragma unroll
  for (int i = 0; i < 4; i++)
    #pragma unroll
    for (int j = 0; j < 4; j++)
      acc[i][j] = (f32x4){0.f, 0.f, 0.f, 0.f};

  const int nk = K >> 5;

  // ---- prologue: stage tiles 0..3; vmcnt(9) forces tile 0 complete ----
  #pragma unroll
  for (int kt = 0; kt < 4; kt++) {
    const int sb = kt * 12288;
    gl_lds16(pa0 + kt*32, LDs + sb + wds);
    gl_lds16(pa1 + kt*32, LDs + sb + 4096 + wds);
    gl_lds16(pb0 + kt*32, LDs + sb + 8192 + wds);
  }
  pa0 += 128; pa1 += 128; pb0 += 128;   // -> tile 4
  asm volatile("s_waitcnt vmcnt(9)" ::: "memory");
  RAW_BARRIER();

  int rb = 0, sb = 49152;               // read tile 0, stage tile 4
  for (int it = 0; it < nk; ++it) {
    // ---- phase 1: B nt0..3 + A mt0,1; stage next A (tile it+4) ----
    bf16x8 bfr[4], afr0, afr1;
    #pragma unroll
    for (int nt = 0; nt < 4; nt++)
      bfr[nt] = *(const bf16x8*)(LDs + rb + boff + nt*512);
    afr0 = *(const bf16x8*)(LDs + rb + aoff);
    afr1 = *(const bf16x8*)(LDs + rb + aoff + 512);
    gl_lds16(pa0, LDs + sb + wds);
    gl_lds16(pa1, LDs + sb + 4096 + wds);
    RAW_BARRIER();
    __builtin_amdgcn_s_setprio(1);
    #pragma unroll
    for (int nt = 0; nt < 4; nt++) {
      acc[0][nt] = __builtin_amdgcn_mfma_f32_16x16x32_bf16(afr0, bfr[nt], acc[0][nt], 0, 0, 0);
      acc[1][nt] = __builtin_amdgcn_mfma_f32_16x16x32_bf16(afr1, bfr[nt], acc[1][nt], 0, 0, 0);
    }
    __builtin_amdgcn_s_setprio(0);
    RAW_BARRIER();

    // ---- phase 2: A mt2,3; stage next B; vmcnt(9) forces tile it+1 ----
    afr0 = *(const bf16x8*)(LDs + rb + aoff + 1024);
    afr1 = *(const bf16x8*)(LDs + rb + aoff + 1536);
    gl_lds16(pb0, LDs + sb + 8192 + wds);
    asm volatile("s_waitcnt vmcnt(9)" ::: "memory");
    RAW_BARRIER();
    __builtin_amdgcn_s_setprio(1);
    #pragma unroll
    for (int nt = 0; nt < 4; nt++) {
      acc[2][nt] = __builtin_amdgcn_mfma_f32_16x16x32_bf16(afr0, bfr[nt], acc[2][nt], 0, 0, 0);
      acc[3][nt] = __builtin_amdgcn_mfma_f32_16x16x32_bf16(afr1, bfr[nt], acc[3][nt], 0, 0, 0);
    }
    __builtin_amdgcn_s_setprio(0);
    RAW_BARRIER();

    if (it + 5 < nk) { pa0 += 32; pa1 += 32; pb0 += 32; }   // clamp (dummy tail)
    rb += 12288; if (rb == 61440) rb = 0;
    sb += 12288; if (sb == 61440) sb = 0;
  }

  #pragma unroll
  for (int nt = 0; nt < 4; nt++) {
    const int col = bn + (wn << 6) + nt*16 + l16;
    const float bv = bias[col];
    #pragma unroll
    for (int mt = 0; mt < 4; mt++) {
      #pragma unroll
      for (int i = 0; i < 4; i++) {
        const int row = bm + (wm << 6) + mt*16 + quad*4 + i;
        float v = (acc[mt][nt][i] + bv) * scale;
        if (RELU) v = fmaxf(v, 0.0f);
        C[(size_t)row * N + col] = (u16)f2bf(v);
      }
    }
  }
}

// ---------------- V transpose v3 (LDS-tiled + XOR group swizzle) ------------
__global__ __launch_bounds__(256) void transpose_v(
    const u16* __restrict__ V, u16* __restrict__ Vt)
{
  __shared__ unsigned T32[64][36];
  const int t  = threadIdx.x;
  const int bh = blockIdx.y;
  const int b = bh >> 4, h = bh & 15;
  const int lblk = blockIdx.x << 6;

  // phase 1: read 16 d per thread, write two swizzled uint4 d-pair groups
  {
    const int il = t >> 2;             // 0..63
    const int c  = (t & 3) << 4;       // d offset 0,16,32,48
    const u16* src = V + ((size_t)(lblk + il) * B_ + b) * E_ + h*64 + c;
    uint4 u0 = *(const uint4*)src;
    uint4 u1 = *(const uint4*)(src + 8);
    const int g0 = (t & 3) << 1;
    const int sw = il >> 4;            // 0..3
    *(uint4*)&T32[il][((g0    ) ^ sw) << 2] = u0;
    *(uint4*)&T32[il][((g0 + 1) ^ sw) << 2] = u1;
  }
  __syncthreads();

  // phase 2: read transposed (conflict-free), store coalesced rows of Vt
  {
    const int d  = t >> 2;             // 0..63
    const int ls = (t & 3) << 4;       // l offset 0,16,32,48
    const int dp = d >> 1, hi = d & 1;
    const int pc = dp ^ ((t & 3) << 2);
    unsigned o[16];
    #pragma unroll
    for (int j = 0; j < 16; j++) {
      unsigned wv = T32[ls + j][pc];
      o[j] = hi ? (wv >> 16) : (wv & 0xffffu);
    }
    uint4 v0, v1;
    v0.x = o[0]  | (o[1]  << 16); v0.y = o[2]  | (o[3]  << 16);
    v0.z = o[4]  | (o[5]  << 16); v0.w = o[6]  | (o[7]  << 16);
    v1.x = o[8]  | (o[9]  << 16); v1.y = o[10] | (o[11] << 16);
    v1.z = o[12] | (o[13] << 16); v1.w = o[14] | (o[15] << 16);
    u16* dst = Vt + (size_t)(bh*64 + d) * S_ + lblk + ls;
    *(uint4*)dst       = v0;
    *(uint4*)(dst + 8) = v1;
  }
}

// ---------------- MFMA flash attention v5b ----------------
template<int CAUSAL>
__global__ __launch_bounds__(256, 4) void attn_mfma(
    const u16* __restrict__ Q,
    const u16* __restrict__ Kg,
    const u16* __restrict__ Vt,
    u16* __restrict__ O,
    int Skv)
{
  __shared__ __align__(16) u16 Tile[16384];   // 32 KB
  const int tid  = threadIdx.x;
  const int lane = tid & 63;
  const int w    = tid >> 6;
  const int l16  = lane & 15;
  const int quad = lane >> 4;
  const int bh = blockIdx.x;
  const int b = bh >> 4, h = bh & 15;
  const int y = blockIdx.y;
  const int q0 = (CAUSAL ? ((y < 8) ? (15 - 2*y) : (2*y - 16)) : y) << 7;
  const int wq = q0 + w*32;

  bf16x8 qf[2][2];
  #pragma unroll
  for (int h2 = 0; h2 < 2; h2++) {
    const size_t qoff = ((size_t)(wq + h2*16 + l16) * B_ + b) * E_ + h*64;
    qf[h2][0] = *(const bf16x8*)(Q + qoff + quad*8);
    qf[h2][1] = *(const bf16x8*)(Q + qoff + 32 + quad*8);
  }

  const uint4 ones_u = {0x3F803F80u, 0x3F803F80u, 0x3F803F80u, 0x3F803F80u};
  const bf16x8 ones = *(const bf16x8*)&ones_u;

  f32x4 oacc[2][4];
  #pragma unroll
  for (int h2 = 0; h2 < 2; h2++)
    #pragma unroll
    for (int i = 0; i < 4; i++) oacc[h2][i] = (f32x4){0.f,0.f,0.f,0.f};
  f32x4 lsacc[2];
  lsacc[0] = (f32x4){0.f,0.f,0.f,0.f};
  lsacc[1] = (f32x4){0.f,0.f,0.f,0.f};

  const int lrow = lane >> 3;
  const int lchunk = (lane & 7) ^ lrow;
  const u16* kp = Kg + ((size_t)(16*w + lrow) * B_ + b) * E_ + h*64 + lchunk*8;
  const u16* vp = Vt + (size_t)(bh*64 + 16*w + lrow) * Skv + lchunk*8;
  const size_t kRow8 = (size_t)8 * B_ * E_;
  const size_t kTile = (size_t)64 * B_ * E_;
  u16* ldsK = Tile + w*1024;
  u16* ldsV = Tile + 4096 + w*1024;

  const int pbase = 8192 + w*2048;
  int aKV[2], aW[4];
  #pragma unroll
  for (int kh = 0; kh < 2; kh++)
    aKV[kh] = l16*64 + (((kh*4 + quad) ^ (l16 & 7)) << 3);
  #pragma unroll
  for (int st = 0; st < 4; st++)
    aW[st] = pbase + l16*64 +
             ((((st*2) + (quad >> 1)) ^ (l16 & 7)) << 3) + ((quad & 1) << 2);

  const int send = CAUSAL ? (q0 + 128) : Skv;
  for (int s0 = 0; s0 < send; s0 += 64) {
    __syncthreads();
    gl_lds16(kp,         ldsK);
    gl_lds16(kp + kRow8, ldsK + 512);
    gl_lds16(vp,         ldsV);
    gl_lds16(vp + 8*Skv, ldsV + 512);
    kp += kTile; vp += 64;
    __syncthreads();

    if (CAUSAL && s0 >= wq + 32) continue;

    f32x4 sacc[2][4];
    #pragma unroll
    for (int h2 = 0; h2 < 2; h2++)
      #pragma unroll
      for (int st = 0; st < 4; st++) sacc[h2][st] = (f32x4){0.f,0.f,0.f,0.f};
    #pragma unroll
    for (int kh = 0; kh < 2; kh++)
      #pragma unroll
      for (int st = 0; st < 4; st++) {
        bf16x8 kf = *(const bf16x8*)(Tile + aKV[kh] + st*1024);
        sacc[0][st] = __builtin_amdgcn_mfma_f32_16x16x32_bf16(kf, qf[0][kh], sacc[0][st], 0, 0, 0);
        sacc[1][st] = __builtin_amdgcn_mfma_f32_16x16x32_bf16(kf, qf[1][kh], sacc[1][st], 0, 0, 0);
      }

    #pragma unroll
    for (int h2 = 0; h2 < 2; h2++) {
      float p[16];
      #pragma unroll
      for (int st = 0; st < 4; st++)
        #pragma unroll
        for (int r = 0; r < 4; r++) p[st*4+r] = sacc[h2][st][r];
      if (CAUSAL && s0 + 63 > wq + h2*16) {
        const int qa = wq + h2*16 + l16;
        #pragma unroll
        for (int st = 0; st < 4; st++)
          #pragma unroll
          for (int r = 0; r < 4; r++)
            if (s0 + st*16 + quad*4 + r > qa) p[st*4+r] = -3e38f;
      }
      #pragma unroll
      for (int i = 0; i < 16; i++) p[i] = __builtin_amdgcn_exp2f(p[i]);

      #pragma unroll
      for (int st = 0; st < 4; st++) {
        uint2 d;
        d.x = __builtin_amdgcn_perm(__float_as_uint(p[st*4+1]), __float_as_uint(p[st*4+0]), 0x07060302u);
        d.y = __builtin_amdgcn_perm(__float_as_uint(p[st*4+3]), __float_as_uint(p[st*4+2]), 0x07060302u);
        *(uint2*)(Tile + aW[st] + h2*1024) = d;
      }
    }

    #pragma unroll
    for (int kh = 0; kh < 2; kh++) {
      bf16x8 pf[2];
      #pragma unroll
      for (int h2 = 0; h2 < 2; h2++)
        pf[h2] = *(const bf16x8*)(Tile + pbase + h2*1024 + aKV[kh]);
      lsacc[0] = __builtin_amdgcn_mfma_f32_16x16x32_bf16(pf[0], ones, lsacc[0], 0, 0, 0);
      lsacc[1] = __builtin_amdgcn_mfma_f32_16x16x32_bf16(pf[1], ones, lsacc[1], 0, 0, 0);
      #pragma unroll
      for (int dt = 0; dt < 4; dt++) {
        bf16x8 vf = *(const bf16x8*)(Tile + 4096 + aKV[kh] + dt*1024);
        #pragma unroll
        for (int h2 = 0; h2 < 2; h2++)
          oacc[h2][dt] = __builtin_amdgcn_mfma_f32_16x16x32_bf16(pf[h2], vf, oacc[h2][dt], 0, 0, 0);
      }
    }
  }

  // ---- epilogue: lane-local normalize (lsacc shares oacc's C-layout) ----
  #pragma unroll
  for (int h2 = 0; h2 < 2; h2++) {
    #pragma unroll
    for (int r = 0; r < 4; r++) {
      const float inv = 1.0f / lsacc[h2][r];
      const int qg = wq + h2*16 + quad*4 + r;
      const size_t orow = ((size_t)qg * B_ + b) * E_ + h*64;
      #pragma unroll
      for (int dt = 0; dt < 4; dt++)
        O[orow + dt*16 + l16] = (u16)f2bf(oacc[h2][dt][r] * inv);
    }
  }
}

// ---------------- residual add + LayerNorm ----------------
template<int RF32>
__global__ __launch_bounds__(256) void add_ln(
    const u16* __restrict__ X,
    const float* __restrict__ Rf, const u16* __restrict__ Rb,
    const float* __restrict__ g, const float* __restrict__ be,
    float* __restrict__ outF, u16* __restrict__ outB)
{
  const int row = blockIdx.x;
  const int tid = threadIdx.x;
  const size_t base = (size_t)row * E_;
  uint2 xu = *(const uint2*)(X + base + tid*4);
  float x0 = bflo(xu.x), x1 = bfhi(xu.x), x2 = bflo(xu.y), x3 = bfhi(xu.y);
  float r0, r1, r2, r3;
  if (RF32) {
    float4 rv = *(const float4*)(Rf + base + tid*4);
    r0 = rv.x; r1 = rv.y; r2 = rv.z; r3 = rv.w;
  } else {
    uint2 ru = *(const uint2*)(Rb + base + tid*4);
    r0 = bflo(ru.x); r1 = bfhi(ru.x); r2 = bflo(ru.y); r3 = bfhi(ru.y);
  }
  const float v0 = x0 + r0, v1 = x1 + r1, v2 = x2 + r2, v3 = x3 + r3;
  float s  = v0 + v1 + v2 + v3;
  float s2 = v0*v0 + v1*v1 + v2*v2 + v3*v3;
  #pragma unroll
  for (int off = 32; off >= 1; off >>= 1) {
    s  += __shfl_down(s,  off);
    s2 += __shfl_down(s2, off);
  }
  __shared__ float ps[4], ps2[4];
  const int wv = tid >> 6, lane = tid & 63;
  if (lane == 0) { ps[wv] = s; ps2[wv] = s2; }
  __syncthreads();
  const float ts  = ps[0] + ps[1] + ps[2] + ps[3];
  const float ts2 = ps2[0] + ps2[1] + ps2[2] + ps2[3];
  const float mu  = ts * (1.0f / E_);
  const float var = ts2 * (1.0f / E_) - mu * mu;
  const float rsq = rsqrtf(var + 1e-5f);
  float4 gv = *(const float4*)(g  + tid*4);
  float4 bv = *(const float4*)(be + tid*4);
  const float o0 = (v0 - mu) * rsq * gv.x + bv.x;
  const float o1 = (v1 - mu) * rsq * gv.y + bv.y;
  const float o2 = (v2 - mu) * rsq * gv.z + bv.z;
  const float o3 = (v3 - mu) * rsq * gv.w + bv.w;
  if (outF) {
    float4 ov; ov.x = o0; ov.y = o1; ov.z = o2; ov.w = o3;
    *(float4*)(outF + base + tid*4) = ov;
  }
  if (outB) {
    uint2 u;
    u.x = f2bf(o0) | (f2bf(o1) << 16);
    u.y = f2bf(o2) | (f2bf(o3) << 16);
    *(uint2*)(outB + base + tid*4) = u;
  }
}

// ---------------- driver ----------------
extern "C" void kernel_launch(void* const* d_in, const int* in_sizes, int n_in,
                              void* d_out, int out_size, void* d_ws, size_t ws_size,
                              hipStream_t stream) {
  (void)in_sizes; (void)n_in; (void)out_size; (void)ws_size;
  const float* tgt  = (const float*)d_in[0];
  const float* mem  = (const float*)d_in[1];
  const float* saWq = (const float*)d_in[3];  const float* sabq = (const float*)d_in[4];
  const float* saWk = (const float*)d_in[5];  const float* sabk = (const float*)d_in[6];
  const float* saWv = (const float*)d_in[7];  const float* sabv = (const float*)d_in[8];
  const float* saWo = (const float*)d_in[9];  const float* sabo = (const float*)d_in[10];
  const float* caWq = (const float*)d_in[11]; const float* cabq = (const float*)d_in[12];
  const float* caWk = (const float*)d_in[13]; const float* cabk = (const float*)d_in[14];
  const float* caWv = (const float*)d_in[15]; const float* cabv = (const float*)d_in[16];
  const float* caWo = (const float*)d_in[17]; const float* cabo = (const float*)d_in[18];
  const float* W1   = (const float*)d_in[19]; const float* b1   = (const float*)d_in[20];
  const float* W2   = (const float*)d_in[21]; const float* b2   = (const float*)d_in[22];
  const float* ln1g = (const float*)d_in[23]; const float* ln1b = (const float*)d_in[24];
  const float* ln2g = (const float*)d_in[25]; const float* ln2b = (const float*)d_in[26];
  const float* ln3g = (const float*)d_in[27]; const float* ln3b = (const float*)d_in[28];
  float* out = (float*)d_out;

  static bool attr_done = false;
  if (!attr_done) {
    (void)hipFuncSetAttribute(reinterpret_cast<const void*>(&gemm256<0,3>),
                              hipFuncAttributeMaxDynamicSharedMemorySize, 131072);
    (void)hipFuncSetAttribute(reinterpret_cast<const void*>(&gemm256<0,2>),
                              hipFuncAttributeMaxDynamicSharedMemorySize, 131072);
    (void)hipFuncSetAttribute(reinterpret_cast<const void*>(&gemm256<1,1>),
                              hipFuncAttributeMaxDynamicSharedMemorySize, 131072);
    (void)hipFuncSetAttribute(reinterpret_cast<const void*>(&gemm256n<0>),
                              hipFuncAttributeMaxDynamicSharedMemorySize, 122880);
    attr_done = true;
  }

  char* wsp = (char*)d_ws;
  const size_t MB16 = (size_t)16 * 1024 * 1024;
  u16* A  = (u16*)(wsp + 0 * MB16);
  u16* Cq = (u16*)(wsp + 1 * MB16);
  u16* Bm = (u16*)(wsp + 2 * MB16);
  u16* Dk = (u16*)(wsp + 3 * MB16);
  u16* Ev = (u16*)(wsp + 4 * MB16);
  u16* Ff = (u16*)(wsp + 5 * MB16);
  u16* wS = (u16*)(wsp + 6 * MB16);
  u16* hb = Cq;
  const int MEG = 1024 * 1024;

  dim3 blk(256);
  dim3 blk512(512);
  dim3 gN1(8, 32);            // 256x128-tile grid, N=1024 (256 blocks)
  dim3 gQKV256(12, 32);       // 256-tile grid, N=3072
  dim3 gKV256(8, 32);         // 256-tile grid, N=2048
  dim3 gFF256(16, 32);        // 256-tile grid, N=4096
  dim3 ga(B_*H_, L_/128);     // Br=128, 1024 blocks
  dim3 gt(S_/64, B_*H_);

  // ---- cvt1: inputs + self-attn weights ----
  {
    CvtTab t{};
    t.s[0] = {tgt,  A,        8192};
    t.s[1] = {mem,  Bm,       16384};
    t.s[2] = {saWq, wS,       17408};
    t.s[3] = {saWk, wS + MEG,   18432};
    t.s[4] = {saWv, wS + 2*MEG, 19456};
    t.s[5] = {saWo, wS + 3*MEG, 20480};
    cvt_all<<<20480, blk, 0, stream>>>(t, 6);
  }

  // ---- self-attention ----
  {
    GTab t{};
    t.o[0]=Cq; t.o[1]=Dk; t.o[2]=Ev;
    t.b[0]=sabq; t.b[1]=sabk; t.b[2]=sabv;
    t.sc[0]=QK_SCALE; t.sc[1]=1.f; t.sc[2]=1.f;
    gemm256<0,3><<<gQKV256, blk512, 131072, stream>>>(A, wS, t, E_, 3*E_);
  }
  transpose_v<<<gt, blk, 0, stream>>>(Ev, Ff);
  attn_mfma<1><<<ga, blk, 0, stream>>>(Cq, Dk, Ff, Cq, S_);
  gemm256n<0><<<gN1, blk512, 122880, stream>>>(Cq, wS + 3*MEG, sabo, Ff, 1.f, E_, E_);
  add_ln<1><<<M_, blk, 0, stream>>>(Ff, tgt, nullptr, ln1g, ln1b, nullptr, A);

  // ---- cvt2: cross-attn weights ----
  {
    CvtTab t{};
    t.s[0] = {caWq, wS,        1024};
    t.s[1] = {caWk, wS + MEG,    2048};
    t.s[2] = {caWv, wS + 2*MEG,  3072};
    t.s[3] = {caWo, wS + 3*MEG,  4096};
    cvt_all<<<4096, blk, 0, stream>>>(t, 4);
  }

  // ---- cross-attention ----
  gemm256n<0><<<gN1, blk512, 122880, stream>>>(A, wS, cabq, Cq, QK_SCALE, E_, E_);
  {
    GTab t{};
    t.o[0]=Dk; t.o[1]=Ev; t.o[2]=Ev;
    t.b[0]=cabk; t.b[1]=cabv; t.b[2]=cabv;
    t.sc[0]=1.f; t.sc[1]=1.f; t.sc[2]=1.f;
    gemm256<0,2><<<gKV256, blk512, 131072, stream>>>(Bm, wS + MEG, t, E_, 2*E_);
  }
  transpose_v<<<gt, blk, 0, stream>>>(Ev, Ff);
  attn_mfma<0><<<ga, blk, 0, stream>>>(Cq, Dk, Ff, Cq, S_);
  gemm256n<0><<<gN1, blk512, 122880, stream>>>(Cq, wS + 3*MEG, cabo, Ff, 1.f, E_, E_);
  add_ln<0><<<M_, blk, 0, stream>>>(Ff, nullptr, A, ln2g, ln2b, nullptr, A);

  // ---- FFN ----
  {
    CvtTab t{};
    t.s[0] = {W1, wS, 4096};
    cvt_all<<<4096, blk, 0, stream>>>(t, 1);
  }
  {
    GTab t{};
    t.o[0]=hb; t.o[1]=hb; t.o[2]=hb;
    t.b[0]=b1; t.b[1]=b1; t.b[2]=b1;
    t.sc[0]=1.f; t.sc[1]=1.f; t.sc[2]=1.f;
    gemm256<1,1><<<gFF256, blk512, 131072, stream>>>(A, wS, t, E_, FF_);
  }
  {
    CvtTab t{};
    t.s[0] = {W2, wS, 4096};
    cvt_all<<<4096, blk, 0, stream>>>(t, 1);
  }
  gemm256n<0><<<gN1, blk512, 122880, stream>>>(hb, wS, b2, Ff, 1.f, FF_, E_);
  add_ln<0><<<M_, blk, 0, stream>>>(Ff, nullptr, A, ln3g, ln3b, out, nullptr);
}

// Round 10
// 717.141 us; speedup vs baseline: 1.0293x; 1.0293x over previous
//
#include <hip/hip_runtime.h>
#include <cstdint>

typedef unsigned short u16;
typedef __bf16 bf16x8 __attribute__((ext_vector_type(8)));
typedef float f32x4 __attribute__((ext_vector_type(4)));

#define L_ 2048
#define S_ 2048
#define B_ 4
#define E_ 1024
#define H_ 16
#define FF_ 4096
#define M_ (L_*B_)

#define QK_SCALE 0.18033688f   /* 1/sqrt(64) * log2(e) */

__device__ __forceinline__ unsigned f2bf(float f) {
  unsigned u = __float_as_uint(f);
  return (u + 0x7fffu + ((u >> 16) & 1u)) >> 16;
}
__device__ __forceinline__ float bflo(unsigned u){ return __uint_as_float(u << 16); }
__device__ __forceinline__ float bfhi(unsigned u){ return __uint_as_float(u & 0xffff0000u); }

// ---------------- batched f32 -> bf16 conversion ----------------
struct CvtSeg { const float* src; u16* dst; int blk_end; };
struct CvtTab { CvtSeg s[6]; };

__global__ __launch_bounds__(256) void cvt_all(CvtTab t, int nseg) {
  const int blk = blockIdx.x;
  int k = 0;
  while (k < nseg - 1 && blk >= t.s[k].blk_end) k++;
  const int b0 = (k == 0) ? 0 : t.s[k-1].blk_end;
  const int off = (blk - b0) * 1024 + threadIdx.x * 4;
  float4 f = *(const float4*)(t.s[k].src + off);
  uint2 u;
  u.x = f2bf(f.x) | (f2bf(f.y) << 16);
  u.y = f2bf(f.z) | (f2bf(f.w) << 16);
  *(uint2*)(t.s[k].dst + off) = u;
}

// ---------------- shared helpers ----------------
struct GTab { u16* o[3]; const float* b[3]; float sc[3]; };

__device__ __forceinline__ void gl_lds16(const u16* g, u16* l) {
  __builtin_amdgcn_global_load_lds(
      (const __attribute__((address_space(1))) unsigned int*)g,
      (__attribute__((address_space(3))) unsigned int*)l, 16, 0, 0);
}

// Compiler-fenced raw barrier: no vmcnt(0) drain (unlike __syncthreads()).
#define RAW_BARRIER() do { \
  asm volatile("" ::: "memory"); \
  __builtin_amdgcn_s_barrier(); \
  asm volatile("" ::: "memory"); \
} while (0)

// ---------------- 256x256-tile counted-vmcnt GEMM ----------------
// R9 ERRATA: XCD remap on THIS kernel regressed (+6% FFN1): FETCH fell
// 74->49 MB but WRITE rose 142->162 (co-dispatch write footprint scattered).
// Remap only pays when reads >> writes (gemm256n/FFN2); reverted here.
// R10: epilogue rewritten -- stage C-subtile in LDS (stride 72 el: b128
// reads bank-uniform, u16 writes <=2-way) then 16 full-line uint4 stores
// per thread instead of 128 scalar u16 stores (which caused the 2.2x WRITE
// amplification + C-line RMW fetches).
template<int RELU, int NG>
__global__ __launch_bounds__(512, 2) void gemm256(
    const u16* __restrict__ A,
    const u16* __restrict__ Bw,
    GTab t, int K, int N)
{
  extern __shared__ __align__(16) u16 LDs[];   // 65536 u16 = 128 KB
  const int tid  = threadIdx.x;
  const int lane = tid & 63;
  const int quad = lane >> 4;
  const int l16  = lane & 15;
  const int w    = tid >> 6;
  const int wm   = w >> 2;            // 0..1  (row half)
  const int wn   = w & 3;             // 0..3  (col quarter)
  const int bm = blockIdx.y << 8;
  const int bn = blockIdx.x << 8;

  const int grp = (NG > 1) ? ((int)blockIdx.x >> 2) : 0;
  u16* Cb = t.o[grp];
  const float* bias = t.b[grp];
  const float scale = t.sc[grp];
  const int ld = (NG > 1) ? 1024 : N;

  const int srow = (w << 4) + (lane >> 2);
  const int cg8  = ((lane & 3) ^ ((lane >> 3) & 3)) << 3;
  const u16* pa0 = A  + (size_t)(bm + srow) * K + cg8;          // A rows [0,128)
  const u16* pa1 = pa0 + (size_t)128 * K;                        // A rows [128,256)
  const u16* pb0 = Bw + (size_t)(bn + srow) * K + cg8;          // B rows [0,128)
  const u16* pb1 = pb0 + (size_t)128 * K;                        // B rows [128,256)
  const int wds = w << 9;  // wave's 1KB slice (elements) within an 8KB half

  const int swz  = (quad ^ ((l16 >> 1) & 3)) << 3;
  const int aoff = ((wm << 7) + l16) * 32 + swz;            // + mt*512
  const int boff = 8192 + ((wn << 6) + l16) * 32 + swz;     // + nt*512

  f32x4 acc[8][4];
  #pragma unroll
  for (int i = 0; i < 8; i++)
    #pragma unroll
    for (int j = 0; j < 4; j++)
      acc[i][j] = (f32x4){0.f, 0.f, 0.f, 0.f};

  const int nk = K >> 5;

  #pragma unroll
  for (int kt = 0; kt < 3; kt++) {
    const int sb = kt << 14;
    gl_lds16(pa0 + kt*32, LDs + sb + wds);
    gl_lds16(pa1 + kt*32, LDs + sb + 4096  + wds);
    gl_lds16(pb0 + kt*32, LDs + sb + 8192  + wds);
    gl_lds16(pb1 + kt*32, LDs + sb + 12288 + wds);
  }
  pa0 += 96; pa1 += 96; pb0 += 96; pb1 += 96;   // -> tile 3
  asm volatile("s_waitcnt vmcnt(8)" ::: "memory");
  RAW_BARRIER();

  for (int it = 0; it < nk; ++it) {
    const int rb = (it & 3) << 14;          // read buffer (tile it)
    const int sb = ((it + 3) & 3) << 14;    // stage buffer (tile it+3 / dummy)

    bf16x8 bfr[4], afr[4];
    #pragma unroll
    for (int nt = 0; nt < 4; nt++)
      bfr[nt] = *(const bf16x8*)(LDs + rb + boff + nt*512);
    #pragma unroll
    for (int mt = 0; mt < 4; mt++)
      afr[mt] = *(const bf16x8*)(LDs + rb + aoff + mt*512);
    gl_lds16(pa0, LDs + sb + wds);
    gl_lds16(pa1, LDs + sb + 4096 + wds);
    RAW_BARRIER();
    __builtin_amdgcn_s_setprio(1);
    #pragma unroll
    for (int mt = 0; mt < 4; mt++)
      #pragma unroll
      for (int nt = 0; nt < 4; nt++)
        acc[mt][nt] = __builtin_amdgcn_mfma_f32_16x16x32_bf16(afr[mt], bfr[nt], acc[mt][nt], 0, 0, 0);
    __builtin_amdgcn_s_setprio(0);
    RAW_BARRIER();

    #pragma unroll
    for (int mt = 0; mt < 4; mt++)
      afr[mt] = *(const bf16x8*)(LDs + rb + aoff + (4 + mt)*512);
    gl_lds16(pb0, LDs + sb + 8192  + wds);
    gl_lds16(pb1, LDs + sb + 12288 + wds);
    asm volatile("s_waitcnt vmcnt(8)" ::: "memory");   // forces ALL of tile it+1
    RAW_BARRIER();
    __builtin_amdgcn_s_setprio(1);
    #pragma unroll
    for (int mt = 0; mt < 4; mt++)
      #pragma unroll
      for (int nt = 0; nt < 4; nt++)
        acc[4 + mt][nt] = __builtin_amdgcn_mfma_f32_16x16x32_bf16(afr[mt], bfr[nt], acc[4 + mt][nt], 0, 0, 0);
    __builtin_amdgcn_s_setprio(0);
    RAW_BARRIER();

    if (it + 4 < nk) { pa0 += 32; pa1 += 32; pb0 += 32; pb1 += 32; }
  }

  // ---- epilogue: LDS-repack -> full-line b128 C stores ----
  // Per wave: stage 64x64 half-tile at stride 72 el (144B, 16B-aligned rows;
  // b128 reads distribute EXACTLY 8 dwords/bank; u16 writes <=2-way).
  // 2 halves x (64 ds_write_b16 rounds... 64 scalar LDS writes + 8 uint4
  // reads + 8 uint4 full-line global stores) replaces 128 scalar C stores.
  float bv[4];
  const int colb  = bn + (wn << 6);
  const int ocolb = (NG > 1) ? (colb & 1023) : colb;
  #pragma unroll
  for (int nt = 0; nt < 4; nt++)
    bv[nt] = bias[ocolb + nt*16 + l16];

  u16* stg = LDs + w * 4608;                 // 64 rows x 72 el per wave (9216B)
  const int srd = (lane >> 3) * 72 + ((lane & 7) << 3);
  const int sc8 = (lane & 7) << 3;
  RAW_BARRIER();                             // all waves' K-loop LDS reads done
  #pragma unroll
  for (int half = 0; half < 2; half++) {
    #pragma unroll
    for (int mt = 0; mt < 4; mt++)
      #pragma unroll
      for (int nt = 0; nt < 4; nt++)
        #pragma unroll
        for (int i = 0; i < 4; i++) {
          float v = (acc[half*4 + mt][nt][i] + bv[nt]) * scale;
          if (RELU) v = fmaxf(v, 0.0f);
          stg[(mt*16 + quad*4 + i)*72 + nt*16 + l16] = (u16)f2bf(v);
        }
    #pragma unroll
    for (int oct = 0; oct < 8; oct++) {
      uint4 vv = *(const uint4*)(stg + oct*576 + srd);
      u16* dst = Cb + (size_t)(bm + (wm << 7) + half*64 + oct*8 + (lane >> 3)) * ld
                    + ocolb + sc8;
      *(uint4*)dst = vv;
    }
    // half 1 overwrites this wave's own region only; per-wave DS ops are
    // in-order, no barrier needed.
  }
}

// ---------------- 256x128-tile counted-vmcnt GEMM (N=1024 outputs) ----------
// R7 remap kept (reads >> writes here: A 64MB vs C 16MB -> remap won, R8).
template<int RELU>
__global__ __launch_bounds__(512, 2) void gemm256n(
    const u16* __restrict__ A,
    const u16* __restrict__ Bw,
    const float* __restrict__ bias,
    u16* __restrict__ C,
    float scale, int K, int N)
{
  extern __shared__ __align__(16) u16 LDs[];   // 61440 u16 = 120 KB (5 x 24KB)
  const int tid  = threadIdx.x;
  const int lane = tid & 63;
  const int quad = lane >> 4;
  const int l16  = lane & 15;
  const int w    = tid >> 6;
  const int wm   = w >> 1;            // 0..3  (row quarter, 64 rows)
  const int wn   = w & 1;             // 0..1  (col half, 64 cols)

  // XCD-locality remap (grid is (8,32); XCD = (by*8+bx)%8 = bx)
  const int bx = blockIdx.x, by = blockIdx.y;
  const int bmq = (bx << 2) + (by & 3);   // 0..31, XCD bx -> bm-stripe [4bx,4bx+4)
  const int bnq = by >> 2;                // 0..7
  const int bm = bmq << 8;     // 256 rows
  const int bn = bnq << 7;     // 128 cols

  const int srow = (w << 4) + (lane >> 2);                    // 0..127
  const int cg8  = ((lane & 3) ^ ((lane >> 3) & 3)) << 3;
  const u16* pa0 = A  + (size_t)(bm + srow) * K + cg8;        // A rows [0,128)
  const u16* pa1 = pa0 + (size_t)128 * K;                      // A rows [128,256)
  const u16* pb0 = Bw + (size_t)(bn + srow) * K + cg8;        // B rows [0,128)
  const int wds = w << 9;

  const int swz  = (quad ^ ((l16 >> 1) & 3)) << 3;
  const int aoff = ((wm << 6) + l16) * 32 + swz;            // + mt*512
  const int boff = 8192 + ((wn << 6) + l16) * 32 + swz;     // + nt*512

  f32x4 acc[4][4];
  #pragma unroll
  for (int i = 0; i < 4; i++)
    #pragma unroll
    for (int j = 0; j < 4; j++)
      acc[i][j] = (f32x4){0.f, 0.f, 0.f, 0.f};

  const int nk = K >> 5;

  // ---- prologue: stage tiles 0..3; vmcnt(9) forces tile 0 complete ----
  #pragma unroll
  for (int kt = 0; kt < 4; kt++) {
    const int sb = kt * 12288;
    gl_lds16(pa0 + kt*32, LDs + sb + wds);
    gl_lds16(pa1 + kt*32, LDs + sb + 4096 + wds);
    gl_lds16(pb0 + kt*32, LDs + sb + 8192 + wds);
  }
  pa0 += 128; pa1 += 128; pb0 += 128;   // -> tile 4
  asm volatile("s_waitcnt vmcnt(9)" ::: "memory");
  RAW_BARRIER();

  int rb = 0, sb = 49152;               // read tile 0, stage tile 4
  for (int it = 0; it < nk; ++it) {
    // ---- phase 1: B nt0..3 + A mt0,1; stage next A (tile it+4) ----
    bf16x8 bfr[4], afr0, afr1;
    #pragma unroll
    for (int nt = 0; nt < 4; nt++)
      bfr[nt] = *(const bf16x8*)(LDs + rb + boff + nt*512);
    afr0 = *(const bf16x8*)(LDs + rb + aoff);
    afr1 = *(const bf16x8*)(LDs + rb + aoff + 512);
    gl_lds16(pa0, LDs + sb + wds);
    gl_lds16(pa1, LDs + sb + 4096 + wds);
    RAW_BARRIER();
    __builtin_amdgcn_s_setprio(1);
    #pragma unroll
    for (int nt = 0; nt < 4; nt++) {
      acc[0][nt] = __builtin_amdgcn_mfma_f32_16x16x32_bf16(afr0, bfr[nt], acc[0][nt], 0, 0, 0);
      acc[1][nt] = __builtin_amdgcn_mfma_f32_16x16x32_bf16(afr1, bfr[nt], acc[1][nt], 0, 0, 0);
    }
    __builtin_amdgcn_s_setprio(0);
    RAW_BARRIER();

    // ---- phase 2: A mt2,3; stage next B; vmcnt(9) forces tile it+1 ----
    afr0 = *(const bf16x8*)(LDs + rb + aoff + 1024);
    afr1 = *(const bf16x8*)(LDs + rb + aoff + 1536);
    gl_lds16(pb0, LDs + sb + 8192 + wds);
    asm volatile("s_waitcnt vmcnt(9)" ::: "memory");
    RAW_BARRIER();
    __builtin_amdgcn_s_setprio(1);
    #pragma unroll
    for (int nt = 0; nt < 4; nt++) {
      acc[2][nt] = __builtin_amdgcn_mfma_f32_16x16x32_bf16(afr0, bfr[nt], acc[2][nt], 0, 0, 0);
      acc[3][nt] = __builtin_amdgcn_mfma_f32_16x16x32_bf16(afr1, bfr[nt], acc[3][nt], 0, 0, 0);
    }
    __builtin_amdgcn_s_setprio(0);
    RAW_BARRIER();

    if (it + 5 < nk) { pa0 += 32; pa1 += 32; pb0 += 32; }   // clamp (dummy tail)
    rb += 12288; if (rb == 61440) rb = 0;
    sb += 12288; if (sb == 61440) sb = 0;
  }

  #pragma unroll
  for (int nt = 0; nt < 4; nt++) {
    const int col = bn + (wn << 6) + nt*16 + l16;
    const float bv = bias[col];
    #pragma unroll
    for (int mt = 0; mt < 4; mt++) {
      #pragma unroll
      for (int i = 0; i < 4; i++) {
        const int row = bm + (wm << 6) + mt*16 + quad*4 + i;
        float v = (acc[mt][nt][i] + bv) * scale;
        if (RELU) v = fmaxf(v, 0.0f);
        C[(size_t)row * N + col] = (u16)f2bf(v);
      }
    }
  }
}

// ---------------- V transpose v3 (LDS-tiled + XOR group swizzle) ------------
__global__ __launch_bounds__(256) void transpose_v(
    const u16* __restrict__ V, u16* __restrict__ Vt)
{
  __shared__ unsigned T32[64][36];
  const int t  = threadIdx.x;
  const int bh = blockIdx.y;
  const int b = bh >> 4, h = bh & 15;
  const int lblk = blockIdx.x << 6;

  // phase 1: read 16 d per thread, write two swizzled uint4 d-pair groups
  {
    const int il = t >> 2;             // 0..63
    const int c  = (t & 3) << 4;       // d offset 0,16,32,48
    const u16* src = V + ((size_t)(lblk + il) * B_ + b) * E_ + h*64 + c;
    uint4 u0 = *(const uint4*)src;
    uint4 u1 = *(const uint4*)(src + 8);
    const int g0 = (t & 3) << 1;
    const int sw = il >> 4;            // 0..3
    *(uint4*)&T32[il][((g0    ) ^ sw) << 2] = u0;
    *(uint4*)&T32[il][((g0 + 1) ^ sw) << 2] = u1;
  }
  __syncthreads();

  // phase 2: read transposed (conflict-free), store coalesced rows of Vt
  {
    const int d  = t >> 2;             // 0..63
    const int ls = (t & 3) << 4;       // l offset 0,16,32,48
    const int dp = d >> 1, hi = d & 1;
    const int pc = dp ^ ((t & 3) << 2);
    unsigned o[16];
    #pragma unroll
    for (int j = 0; j < 16; j++) {
      unsigned wv = T32[ls + j][pc];
      o[j] = hi ? (wv >> 16) : (wv & 0xffffu);
    }
    uint4 v0, v1;
    v0.x = o[0]  | (o[1]  << 16); v0.y = o[2]  | (o[3]  << 16);
    v0.z = o[4]  | (o[5]  << 16); v0.w = o[6]  | (o[7]  << 16);
    v1.x = o[8]  | (o[9]  << 16); v1.y = o[10] | (o[11] << 16);
    v1.z = o[12] | (o[13] << 16); v1.w = o[14] | (o[15] << 16);
    u16* dst = Vt + (size_t)(bh*64 + d) * S_ + lblk + ls;
    *(uint4*)dst       = v0;
    *(uint4*)(dst + 8) = v1;
  }
}

// ---------------- MFMA flash attention v5b ----------------
template<int CAUSAL>
__global__ __launch_bounds__(256, 4) void attn_mfma(
    const u16* __restrict__ Q,
    const u16* __restrict__ Kg,
    const u16* __restrict__ Vt,
    u16* __restrict__ O,
    int Skv)
{
  __shared__ __align__(16) u16 Tile[16384];   // 32 KB
  const int tid  = threadIdx.x;
  const int lane = tid & 63;
  const int w    = tid >> 6;
  const int l16  = lane & 15;
  const int quad = lane >> 4;
  const int bh = blockIdx.x;
  const int b = bh >> 4, h = bh & 15;
  const int y = blockIdx.y;
  const int q0 = (CAUSAL ? ((y < 8) ? (15 - 2*y) : (2*y - 16)) : y) << 7;
  const int wq = q0 + w*32;

  bf16x8 qf[2][2];
  #pragma unroll
  for (int h2 = 0; h2 < 2; h2++) {
    const size_t qoff = ((size_t)(wq + h2*16 + l16) * B_ + b) * E_ + h*64;
    qf[h2][0] = *(const bf16x8*)(Q + qoff + quad*8);
    qf[h2][1] = *(const bf16x8*)(Q + qoff + 32 + quad*8);
  }

  const uint4 ones_u = {0x3F803F80u, 0x3F803F80u, 0x3F803F80u, 0x3F803F80u};
  const bf16x8 ones = *(const bf16x8*)&ones_u;

  f32x4 oacc[2][4];
  #pragma unroll
  for (int h2 = 0; h2 < 2; h2++)
    #pragma unroll
    for (int i = 0; i < 4; i++) oacc[h2][i] = (f32x4){0.f,0.f,0.f,0.f};
  f32x4 lsacc[2];
  lsacc[0] = (f32x4){0.f,0.f,0.f,0.f};
  lsacc[1] = (f32x4){0.f,0.f,0.f,0.f};

  const int lrow = lane >> 3;
  const int lchunk = (lane & 7) ^ lrow;
  const u16* kp = Kg + ((size_t)(16*w + lrow) * B_ + b) * E_ + h*64 + lchunk*8;
  const u16* vp = Vt + (size_t)(bh*64 + 16*w + lrow) * Skv + lchunk*8;
  const size_t kRow8 = (size_t)8 * B_ * E_;
  const size_t kTile = (size_t)64 * B_ * E_;
  u16* ldsK = Tile + w*1024;
  u16* ldsV = Tile + 4096 + w*1024;

  const int pbase = 8192 + w*2048;
  int aKV[2], aW[4];
  #pragma unroll
  for (int kh = 0; kh < 2; kh++)
    aKV[kh] = l16*64 + (((kh*4 + quad) ^ (l16 & 7)) << 3);
  #pragma unroll
  for (int st = 0; st < 4; st++)
    aW[st] = pbase + l16*64 +
             ((((st*2) + (quad >> 1)) ^ (l16 & 7)) << 3) + ((quad & 1) << 2);

  const int send = CAUSAL ? (q0 + 128) : Skv;
  for (int s0 = 0; s0 < send; s0 += 64) {
    __syncthreads();
    gl_lds16(kp,         ldsK);
    gl_lds16(kp + kRow8, ldsK + 512);
    gl_lds16(vp,         ldsV);
    gl_lds16(vp + 8*Skv, ldsV + 512);
    kp += kTile; vp += 64;
    __syncthreads();

    if (CAUSAL && s0 >= wq + 32) continue;

    f32x4 sacc[2][4];
    #pragma unroll
    for (int h2 = 0; h2 < 2; h2++)
      #pragma unroll
      for (int st = 0; st < 4; st++) sacc[h2][st] = (f32x4){0.f,0.f,0.f,0.f};
    #pragma unroll
    for (int kh = 0; kh < 2; kh++)
      #pragma unroll
      for (int st = 0; st < 4; st++) {
        bf16x8 kf = *(const bf16x8*)(Tile + aKV[kh] + st*1024);
        sacc[0][st] = __builtin_amdgcn_mfma_f32_16x16x32_bf16(kf, qf[0][kh], sacc[0][st], 0, 0, 0);
        sacc[1][st] = __builtin_amdgcn_mfma_f32_16x16x32_bf16(kf, qf[1][kh], sacc[1][st], 0, 0, 0);
      }

    #pragma unroll
    for (int h2 = 0; h2 < 2; h2++) {
      float p[16];
      #pragma unroll
      for (int st = 0; st < 4; st++)
        #pragma unroll
        for (int r = 0; r < 4; r++) p[st*4+r] = sacc[h2][st][r];
      if (CAUSAL && s0 + 63 > wq + h2*16) {
        const int qa = wq + h2*16 + l16;
        #pragma unroll
        for (int st = 0; st < 4; st++)
          #pragma unroll
          for (int r = 0; r < 4; r++)
            if (s0 + st*16 + quad*4 + r > qa) p[st*4+r] = -3e38f;
      }
      #pragma unroll
      for (int i = 0; i < 16; i++) p[i] = __builtin_amdgcn_exp2f(p[i]);

      #pragma unroll
      for (int st = 0; st < 4; st++) {
        uint2 d;
        d.x = __builtin_amdgcn_perm(__float_as_uint(p[st*4+1]), __float_as_uint(p[st*4+0]), 0x07060302u);
        d.y = __builtin_amdgcn_perm(__float_as_uint(p[st*4+3]), __float_as_uint(p[st*4+2]), 0x07060302u);
        *(uint2*)(Tile + aW[st] + h2*1024) = d;
      }
    }

    #pragma unroll
    for (int kh = 0; kh < 2; kh++) {
      bf16x8 pf[2];
      #pragma unroll
      for (int h2 = 0; h2 < 2; h2++)
        pf[h2] = *(const bf16x8*)(Tile + pbase + h2*1024 + aKV[kh]);
      lsacc[0] = __builtin_amdgcn_mfma_f32_16x16x32_bf16(pf[0], ones, lsacc[0], 0, 0, 0);
      lsacc[1] = __builtin_amdgcn_mfma_f32_16x16x32_bf16(pf[1], ones, lsacc[1], 0, 0, 0);
      #pragma unroll
      for (int dt = 0; dt < 4; dt++) {
        bf16x8 vf = *(const bf16x8*)(Tile + 4096 + aKV[kh] + dt*1024);
        #pragma unroll
        for (int h2 = 0; h2 < 2; h2++)
          oacc[h2][dt] = __builtin_amdgcn_mfma_f32_16x16x32_bf16(pf[h2], vf, oacc[h2][dt], 0, 0, 0);
      }
    }
  }

  // ---- epilogue: lane-local normalize (lsacc shares oacc's C-layout) ----
  #pragma unroll
  for (int h2 = 0; h2 < 2; h2++) {
    #pragma unroll
    for (int r = 0; r < 4; r++) {
      const float inv = 1.0f / lsacc[h2][r];
      const int qg = wq + h2*16 + quad*4 + r;
      const size_t orow = ((size_t)qg * B_ + b) * E_ + h*64;
      #pragma unroll
      for (int dt = 0; dt < 4; dt++)
        O[orow + dt*16 + l16] = (u16)f2bf(oacc[h2][dt][r] * inv);
    }
  }
}

// ---------------- residual add + LayerNorm ----------------
template<int RF32>
__global__ __launch_bounds__(256) void add_ln(
    const u16* __restrict__ X,
    const float* __restrict__ Rf, const u16* __restrict__ Rb,
    const float* __restrict__ g, const float* __restrict__ be,
    float* __restrict__ outF, u16* __restrict__ outB)
{
  const int row = blockIdx.x;
  const int tid = threadIdx.x;
  const size_t base = (size_t)row * E_;
  uint2 xu = *(const uint2*)(X + base + tid*4);
  float x0 = bflo(xu.x), x1 = bfhi(xu.x), x2 = bflo(xu.y), x3 = bfhi(xu.y);
  float r0, r1, r2, r3;
  if (RF32) {
    float4 rv = *(const float4*)(Rf + base + tid*4);
    r0 = rv.x; r1 = rv.y; r2 = rv.z; r3 = rv.w;
  } else {
    uint2 ru = *(const uint2*)(Rb + base + tid*4);
    r0 = bflo(ru.x); r1 = bfhi(ru.x); r2 = bflo(ru.y); r3 = bfhi(ru.y);
  }
  const float v0 = x0 + r0, v1 = x1 + r1, v2 = x2 + r2, v3 = x3 + r3;
  float s  = v0 + v1 + v2 + v3;
  float s2 = v0*v0 + v1*v1 + v2*v2 + v3*v3;
  #pragma unroll
  for (int off = 32; off >= 1; off >>= 1) {
    s  += __shfl_down(s,  off);
    s2 += __shfl_down(s2, off);
  }
  __shared__ float ps[4], ps2[4];
  const int wv = tid >> 6, lane = tid & 63;
  if (lane == 0) { ps[wv] = s; ps2[wv] = s2; }
  __syncthreads();
  const float ts  = ps[0] + ps[1] + ps[2] + ps[3];
  const float ts2 = ps2[0] + ps2[1] + ps2[2] + ps2[3];
  const float mu  = ts * (1.0f / E_);
  const float var = ts2 * (1.0f / E_) - mu * mu;
  const float rsq = rsqrtf(var + 1e-5f);
  float4 gv = *(const float4*)(g  + tid*4);
  float4 bv = *(const float4*)(be + tid*4);
  const float o0 = (v0 - mu) * rsq * gv.x + bv.x;
  const float o1 = (v1 - mu) * rsq * gv.y + bv.y;
  const float o2 = (v2 - mu) * rsq * gv.z + bv.z;
  const float o3 = (v3 - mu) * rsq * gv.w + bv.w;
  if (outF) {
    float4 ov; ov.x = o0; ov.y = o1; ov.z = o2; ov.w = o3;
    *(float4*)(outF + base + tid*4) = ov;
  }
  if (outB) {
    uint2 u;
    u.x = f2bf(o0) | (f2bf(o1) << 16);
    u.y = f2bf(o2) | (f2bf(o3) << 16);
    *(uint2*)(outB + base + tid*4) = u;
  }
}

// ---------------- driver ----------------
extern "C" void kernel_launch(void* const* d_in, const int* in_sizes, int n_in,
                              void* d_out, int out_size, void* d_ws, size_t ws_size,
                              hipStream_t stream) {
  (void)in_sizes; (void)n_in; (void)out_size; (void)ws_size;
  const float* tgt  = (const float*)d_in[0];
  const float* mem  = (const float*)d_in[1];
  const float* saWq = (const float*)d_in[3];  const float* sabq = (const float*)d_in[4];
  const float* saWk = (const float*)d_in[5];  const float* sabk = (const float*)d_in[6];
  const float* saWv = (const float*)d_in[7];  const float* sabv = (const float*)d_in[8];
  const float* saWo = (const float*)d_in[9];  const float* sabo = (const float*)d_in[10];
  const float* caWq = (const float*)d_in[11]; const float* cabq = (const float*)d_in[12];
  const float* caWk = (const float*)d_in[13]; const float* cabk = (const float*)d_in[14];
  const float* caWv = (const float*)d_in[15]; const float* cabv = (const float*)d_in[16];
  const float* caWo = (const float*)d_in[17]; const float* cabo = (const float*)d_in[18];
  const float* W1   = (const float*)d_in[19]; const float* b1   = (const float*)d_in[20];
  const float* W2   = (const float*)d_in[21]; const float* b2   = (const float*)d_in[22];
  const float* ln1g = (const float*)d_in[23]; const float* ln1b = (const float*)d_in[24];
  const float* ln2g = (const float*)d_in[25]; const float* ln2b = (const float*)d_in[26];
  const float* ln3g = (const float*)d_in[27]; const float* ln3b = (const float*)d_in[28];
  float* out = (float*)d_out;

  static bool attr_done = false;
  if (!attr_done) {
    (void)hipFuncSetAttribute(reinterpret_cast<const void*>(&gemm256<0,3>),
                              hipFuncAttributeMaxDynamicSharedMemorySize, 131072);
    (void)hipFuncSetAttribute(reinterpret_cast<const void*>(&gemm256<0,2>),
                              hipFuncAttributeMaxDynamicSharedMemorySize, 131072);
    (void)hipFuncSetAttribute(reinterpret_cast<const void*>(&gemm256<1,1>),
                              hipFuncAttributeMaxDynamicSharedMemorySize, 131072);
    (void)hipFuncSetAttribute(reinterpret_cast<const void*>(&gemm256n<0>),
                              hipFuncAttributeMaxDynamicSharedMemorySize, 122880);
    attr_done = true;
  }

  char* wsp = (char*)d_ws;
  const size_t MB16 = (size_t)16 * 1024 * 1024;
  u16* A  = (u16*)(wsp + 0 * MB16);
  u16* Cq = (u16*)(wsp + 1 * MB16);
  u16* Bm = (u16*)(wsp + 2 * MB16);
  u16* Dk = (u16*)(wsp + 3 * MB16);
  u16* Ev = (u16*)(wsp + 4 * MB16);
  u16* Ff = (u16*)(wsp + 5 * MB16);
  u16* wS = (u16*)(wsp + 6 * MB16);
  u16* hb = Cq;
  const int MEG = 1024 * 1024;

  dim3 blk(256);
  dim3 blk512(512);
  dim3 gN1(8, 32);            // 256x128-tile grid, N=1024 (256 blocks)
  dim3 gQKV256(12, 32);       // 256-tile grid, N=3072
  dim3 gKV256(8, 32);         // 256-tile grid, N=2048
  dim3 gFF256(16, 32);        // 256-tile grid, N=4096
  dim3 ga(B_*H_, L_/128);     // Br=128, 1024 blocks
  dim3 gt(S_/64, B_*H_);

  // ---- cvt1: inputs + self-attn weights ----
  {
    CvtTab t{};
    t.s[0] = {tgt,  A,        8192};
    t.s[1] = {mem,  Bm,       16384};
    t.s[2] = {saWq, wS,       17408};
    t.s[3] = {saWk, wS + MEG,   18432};
    t.s[4] = {saWv, wS + 2*MEG, 19456};
    t.s[5] = {saWo, wS + 3*MEG, 20480};
    cvt_all<<<20480, blk, 0, stream>>>(t, 6);
  }

  // ---- self-attention ----
  {
    GTab t{};
    t.o[0]=Cq; t.o[1]=Dk; t.o[2]=Ev;
    t.b[0]=sabq; t.b[1]=sabk; t.b[2]=sabv;
    t.sc[0]=QK_SCALE; t.sc[1]=1.f; t.sc[2]=1.f;
    gemm256<0,3><<<gQKV256, blk512, 131072, stream>>>(A, wS, t, E_, 3*E_);
  }
  transpose_v<<<gt, blk, 0, stream>>>(Ev, Ff);
  attn_mfma<1><<<ga, blk, 0, stream>>>(Cq, Dk, Ff, Cq, S_);
  gemm256n<0><<<gN1, blk512, 122880, stream>>>(Cq, wS + 3*MEG, sabo, Ff, 1.f, E_, E_);
  add_ln<1><<<M_, blk, 0, stream>>>(Ff, tgt, nullptr, ln1g, ln1b, nullptr, A);

  // ---- cvt2: cross-attn weights ----
  {
    CvtTab t{};
    t.s[0] = {caWq, wS,        1024};
    t.s[1] = {caWk, wS + MEG,    2048};
    t.s[2] = {caWv, wS + 2*MEG,  3072};
    t.s[3] = {caWo, wS + 3*MEG,  4096};
    cvt_all<<<4096, blk, 0, stream>>>(t, 4);
  }

  // ---- cross-attention ----
  gemm256n<0><<<gN1, blk512, 122880, stream>>>(A, wS, cabq, Cq, QK_SCALE, E_, E_);
  {
    GTab t{};
    t.o[0]=Dk; t.o[1]=Ev; t.o[2]=Ev;
    t.b[0]=cabk; t.b[1]=cabv; t.b[2]=cabv;
    t.sc[0]=1.f; t.sc[1]=1.f; t.sc[2]=1.f;
    gemm256<0,2><<<gKV256, blk512, 131072, stream>>>(Bm, wS + MEG, t, E_, 2*E_);
  }
  transpose_v<<<gt, blk, 0, stream>>>(Ev, Ff);
  attn_mfma<0><<<ga, blk, 0, stream>>>(Cq, Dk, Ff, Cq, S_);
  gemm256n<0><<<gN1, blk512, 122880, stream>>>(Cq, wS + 3*MEG, cabo, Ff, 1.f, E_, E_);
  add_ln<0><<<M_, blk, 0, stream>>>(Ff, nullptr, A, ln2g, ln2b, nullptr, A);

  // ---- FFN ----
  {
    CvtTab t{};
    t.s[0] = {W1, wS, 4096};
    cvt_all<<<4096, blk, 0, stream>>>(t, 1);
  }
  {
    GTab t{};
    t.o[0]=hb; t.o[1]=hb; t.o[2]=hb;
    t.b[0]=b1; t.b[1]=b1; t.b[2]=b1;
    t.sc[0]=1.f; t.sc[1]=1.f; t.sc[2]=1.f;
    gemm256<1,1><<<gFF256, blk512, 131072, stream>>>(A, wS, t, E_, FF_);
  }
  {
    CvtTab t{};
    t.s[0] = {W2, wS, 4096};
    cvt_all<<<4096, blk, 0, stream>>>(t, 1);
  }
  gemm256n<0><<<gN1, blk512, 122880, stream>>>(hb, wS, b2, Ff, 1.f, FF_, E_);
  add_ln<0><<<M_, blk, 0, stream>>>(Ff, nullptr, A, ln3g, ln3b, out, nullptr);
}